// Round 7
// baseline (58.437 us; speedup 1.0000x reference)
//
#include <hip/hip_runtime.h>

#define WI 4096
#define HI 4096
#define WO 4090
#define HO 4090
#define SLOTW 520          // floats per ring slot (need 518, pad to 16B mult)
#define RING 16            // 4 groups of 4 rows
#define SEGROWS 32         // output rows per block

__device__ __forceinline__ void gl_lds16(const float* g, float* l) {
    __builtin_amdgcn_global_load_lds(
        (const __attribute__((address_space(1))) void*)g,
        (__attribute__((address_space(3))) void*)l, 16, 0, 0);
}

// One 4-row step. TC = compile-time representative of t (exact for peeled
// t=0,1; parity representative 2/3 for t>=2: (4*TC+j-ky)&7 == (4*t+j-ky)&7
// since 4t mod 8 depends only on t&1, and all >=0 guards are stable for t>=2).
#define STEP(TC, TR)                                                        \
  {                                                                         \
    const int sb_ = (4*(TR)) & 15;                                          \
    _Pragma("unroll")                                                       \
    for (int j = 0; j < 4; ++j) {                                           \
      const float* lrow_ = ring + (sb_ + j) * SLOTW + 2 * tid;              \
      const float2 q0 = *(const float2*)(lrow_ + 0);                        \
      const float2 q1 = *(const float2*)(lrow_ + 2);                        \
      const float2 q2 = *(const float2*)(lrow_ + 4);                        \
      const float2 q3 = *(const float2*)(lrow_ + 6);                        \
      const float f_[8] = {q0.x,q0.y,q1.x,q1.y,q2.x,q2.y,q3.x,q3.y};        \
      _Pragma("unroll")                                                     \
      for (int ky = 0; ky < 7; ++ky) {                                      \
        if (4*(TC) + j - ky >= 0) {          /* static */                   \
          const int s_ = (4*(TC) + j - ky) & 7;                             \
          _Pragma("unroll")                                                 \
          for (int kx = 0; kx < 7; ++kx) {                                  \
            const float w_ = Wt[ky*7 + kx];                                 \
            a0[s_] += w_ * f_[kx];                                          \
            a1[s_] += w_ * f_[kx + 1];                                      \
          }                                                                 \
        }                                                                   \
      }                                                                     \
      if (4*(TC) + j - 6 >= 0) {             /* static: store exists */     \
        const int ss_  = (4*(TC) + j - 6) & 7;                              \
        const int oyl_ = 4*(TR) + j - 6;                                    \
        const int gy_  = gy0 + oyl_;                                        \
        if (oyl_ < SEGROWS && gy_ < HO) {                                   \
          if (gx + 1 < WO) {                                                \
            float2 o_; o_.x = a0[ss_] + bb; o_.y = a1[ss_] + bb;            \
            *(float2*)(out + (size_t)gy_ * WO + gx) = o_;                   \
          }                                                                 \
        }                                                                   \
        a0[ss_] = 0.f; a1[ss_] = 0.f;                                       \
      }                                                                     \
    }                                                                       \
  }

__global__ __launch_bounds__(256, 4) void conv7x7(
    const float* __restrict__ x, const float* __restrict__ wgt,
    const float* __restrict__ bias, float* __restrict__ out)
{
    __shared__ float ring[RING * SLOTW];   // 33,280 B -> 4 blocks/CU

    const int tid = threadIdx.x;
    const int x0  = blockIdx.x * 512;      // stripe start col (floats)
    const int gy0 = blockIdx.y * SEGROWS;  // first output row of segment
    const int gx  = x0 + 2 * tid;

    // weights + bias: uniform addresses -> SGPR-resident
    float Wt[49];
    #pragma unroll
    for (int i = 0; i < 49; ++i) Wt[i] = wgt[i];
    const float bb = bias[0];

    // --- staging chunk precompute: 520 16B-chunks per 4-row group ---
    const int c1 = tid + 256, c2 = tid + 512;
    const int j0 = tid / 130, j1 = c1 / 130;
    int o0 = tid - j0 * 130, o1 = c1 - j1 * 130, o2 = c2 - 390;
    // right-edge clamp: cols >= WI never feed valid outputs; read col 0 instead
    o0 = (x0 + o0 * 4 + 3 < WI) ? o0 : 0;
    o1 = (x0 + o1 * 4 + 3 < WI) ? o1 : 0;
    o2 = (x0 + o2 * 4 + 3 < WI) ? o2 : 0;

    // stage group g (input rows gy0+4g..+3) into ring slots (4g&15)..+3
    auto STAGE = [&](int g) {
        const int gb = ((4 * g) & 15) * SLOTW;
        const int rb = gy0 + 4 * g;
        int r0 = rb + j0; r0 = r0 < HI ? r0 : HI - 1;
        int r1 = rb + j1; r1 = r1 < HI ? r1 : HI - 1;
        gl_lds16(x + (size_t)r0 * WI + x0 + o0 * 4, ring + gb + tid * 4);
        gl_lds16(x + (size_t)r1 * WI + x0 + o1 * 4, ring + gb + c1 * 4);
        if (tid < 8) {
            int r2 = rb + 3; r2 = r2 < HI ? r2 : HI - 1;
            gl_lds16(x + (size_t)r2 * WI + x0 + o2 * 4, ring + gb + c2 * 4);
        }
    };

    float a0[8], a1[8];
    #pragma unroll
    for (int s = 0; s < 8; ++s) { a0[s] = 0.f; a1[s] = 0.f; }

    // prologue: groups 0,1 staged; one exposed drain per block
    STAGE(0); STAGE(1);
    __syncthreads();

    // steady state: issue STAGE(t+2) AFTER the barrier, then compute group t.
    // The next barrier's vmcnt(0) drain then waits on loads issued a full
    // compute phase (~800 cyc) earlier -> drain ~free (vs R6: 0 cyc earlier).
    STAGE(2); STEP(0, 0);
    __syncthreads();
    STAGE(3); STEP(1, 1);
    __syncthreads();

    for (int u = 1; u < 5; ++u) {
        const int t0 = 2 * u;
        if (t0 + 2 <= 9) STAGE(t0 + 2);
        STEP(2, t0);                 // parity-0 representative
        __syncthreads();
        const int t1 = 2 * u + 1;
        if (t1 + 2 <= 9) STAGE(t1 + 2);
        STEP(3, t1);                 // parity-1 representative
        __syncthreads();
    }
}

extern "C" void kernel_launch(void* const* d_in, const int* in_sizes, int n_in,
                              void* d_out, int out_size, void* d_ws, size_t ws_size,
                              hipStream_t stream) {
    const float* x = (const float*)d_in[0];
    const float* w = (const float*)d_in[1];
    const float* b = (const float*)d_in[2];
    float* out = (float*)d_out;
    // 8 column stripes x 128 row segments = 1024 blocks = exactly 4/CU
    dim3 grid(8, 128);
    conv7x7<<<grid, 256, 0, stream>>>(x, w, b, out);
}

// Round 8
// 47.851 us; speedup vs baseline: 1.2212x; 1.2212x over previous
//
#include <hip/hip_runtime.h>

#define WI 4096
#define HI 4096
#define WO 4090
#define HO 4090
#define SEG 36           // output rows per block
#define SLOTF 2048       // floats per ring slot (4 rows x 512)

#define VMW(n) asm volatile("s_waitcnt vmcnt(" #n ")" ::: "memory")
#define BAR()  __builtin_amdgcn_s_barrier()

__device__ __forceinline__ void gl_lds16(const float* g, float* l) {
    __builtin_amdgcn_global_load_lds(
        (const __attribute__((address_space(1))) void*)g,
        (__attribute__((address_space(3))) void*)l, 16, 0, 0);
}

// Stage 4-row group G: wave w loads input row gy0+4G+w (512 floats = 2 insts).
// Exactly 2 global_load_lds per wave per stage -> vmcnt counting is exact.
#define STAGE(G)                                                            \
  {                                                                         \
    int gy_ = gy0 + 4*(G) + w; gy_ = gy_ < HI ? gy_ : HI - 1;               \
    const float* srcr_ = x + (size_t)gy_ * WI;                              \
    float* ldb_ = ring + ((G) % 5) * SLOTF + w * 512;                       \
    gl_lds16(srcr_ + ca0, ldb_);                                            \
    gl_lds16(srcr_ + ca1, ldb_ + 256);                                      \
  }

// One 4-row compute step. TC = compile-time representative of t (exact for
// t=0,1; parity rep 2/3 for t>=2 -- (4TC+j-ky)&7 == (4t+j-ky)&7 since
// 4t mod 8 depends only on t&1, and the >=0 guards are stable for t>=2).
#define STEP(TC, TR, SB)                                                    \
  {                                                                         \
    _Pragma("unroll")                                                       \
    for (int j = 0; j < 4; ++j) {                                           \
      const float* lrow_ = ring + (SB) + j * 512 + cx2;                     \
      const float2 q0 = *(const float2*)(lrow_ + 0);                        \
      const float2 q1 = *(const float2*)(lrow_ + 2);                        \
      const float2 q2 = *(const float2*)(lrow_ + 4);                        \
      const float2 q3 = *(const float2*)(lrow_ + 6);                        \
      const float f_[8] = {q0.x,q0.y,q1.x,q1.y,q2.x,q2.y,q3.x,q3.y};        \
      _Pragma("unroll")                                                     \
      for (int ky = 0; ky < 7; ++ky) {                                      \
        if (4*(TC) + j - ky >= 0) {          /* static */                   \
          const int s_ = (4*(TC) + j - ky) & 7;                             \
          _Pragma("unroll")                                                 \
          for (int kx = 0; kx < 7; ++kx) {                                  \
            const float w_ = Wt[ky*7 + kx];                                 \
            a0[s_] += w_ * f_[kx];                                          \
            a1[s_] += w_ * f_[kx + 1];                                      \
          }                                                                 \
        }                                                                   \
      }                                                                     \
      if (4*(TC) + j - 6 >= 0) {             /* static: store exists */     \
        const int ss_  = (4*(TC) + j - 6) & 7;                              \
        const int oyl_ = 4*(TR) + j - 6;                                    \
        const int gy_  = gy0 + oyl_;                                        \
        if (stok && oyl_ < SEG && gy_ < HO) {                               \
          float2 o_; o_.x = a0[ss_] + bb; o_.y = a1[ss_] + bb;              \
          *(float2*)(out + (size_t)gy_ * WO + gx) = o_;                     \
        }                                                                   \
        a0[ss_] = 0.f; a1[ss_] = 0.f;                                      \
      }                                                                     \
    }                                                                       \
  }

__global__ __launch_bounds__(256, 4) void conv7x7(
    const float* __restrict__ x, const float* __restrict__ wgt,
    const float* __restrict__ bias, float* __restrict__ out)
{
    __shared__ float ring[5 * SLOTF];      // 40,960 B -> exactly 4 blocks/CU

    const int tid  = threadIdx.x;
    const int lane = tid & 63;
    const int w    = tid >> 6;             // wave id (stages row j=w of group)
    const int x0   = blockIdx.x * 504;     // stripe start col (16B-aligned)
    const int gy0  = blockIdx.y * SEG;

    // weights + bias: uniform addresses -> SGPR-resident
    float Wt[49];
    #pragma unroll
    for (int i = 0; i < 49; ++i) Wt[i] = wgt[i];
    const float bb = bias[0];

    // per-lane staging source cols (clamped to keep 16B loads in-row)
    int ca0 = x0 + lane * 4;        ca0 = ca0 <= 4092 ? ca0 : 4092;
    int ca1 = x0 + 256 + lane * 4;  ca1 = ca1 <= 4092 ? ca1 : 4092;

    // compute-side: 2 cols/thread; threads past col 504 read a safe addr,
    // never store (their cols belong to the next stripe, computed there)
    const int cx2  = (2 * tid <= 504) ? 2 * tid : 504;
    const int gx   = x0 + 2 * tid;
    const bool stok = (2 * tid <= 504) && (gx + 1 < WO);

    float a0[8], a1[8];
    #pragma unroll
    for (int s = 0; s < 8; ++s) { a0[s] = 0.f; a1[s] = 0.f; }

    // prologue: 3 groups in flight
    STAGE(0) STAGE(1) STAGE(2)

    // main loop: vmcnt(4) = stages t+1,t+2 stay in flight (safe lower bound
    // independent of store emission); barrier AFTER the wait makes cross-wave
    // staging visible; STAGE(t+3) issued post-barrier (WAR-safe vs slot t-2).
    VMW(4); BAR(); STAGE(3)  STEP(0, 0, 0)
    VMW(4); BAR(); STAGE(4)  STEP(1, 1, SLOTF)
    VMW(4); BAR(); STAGE(5)  STEP(2, 2, 2*SLOTF)
    VMW(4); BAR(); STAGE(6)  STEP(3, 3, 3*SLOTF)
    VMW(4); BAR(); STAGE(7)  STEP(2, 4, 4*SLOTF)
    VMW(4); BAR(); STAGE(8)  STEP(3, 5, 0)
    VMW(4); BAR(); STAGE(9)  STEP(2, 6, SLOTF)
    VMW(4); BAR(); STAGE(10) STEP(3, 7, 2*SLOTF)
    VMW(4); BAR();           STEP(2, 8, 3*SLOTF)
    VMW(2); BAR();           STEP(3, 9, 4*SLOTF)
    VMW(0); BAR();           STEP(2, 10, 0)
}

extern "C" void kernel_launch(void* const* d_in, const int* in_sizes, int n_in,
                              void* d_out, int out_size, void* d_ws, size_t ws_size,
                              hipStream_t stream) {
    const float* x = (const float*)d_in[0];
    const float* w = (const float*)d_in[1];
    const float* b = (const float*)d_in[2];
    float* out = (float*)d_out;
    // 9 stripes x 504 cols (last partial), 114 segments x 36 rows
    dim3 grid(9, 114);
    conv7x7<<<grid, 256, 0, stream>>>(x, w, b, out);
}